// Round 1
// baseline (1658.345 us; speedup 1.0000x reference)
//
#include <hip/hip_runtime.h>

// ST_GCNA: 3-head GAT (pygat style), b=16384, N=22 nodes, F=H=192.
// Strategy: bf16 MFMA for the 3 big GEMMs (W pre-swizzled to B-fragment-major
// in d_ws by a prep kernel), fp32 attention/softmax/att@Wh. One block/sample.

typedef __attribute__((ext_vector_type(8))) short s16x8;
typedef __attribute__((ext_vector_type(4))) float f32x4;

constexpr int NN  = 22;    // nodes
constexpr int FF  = 192;   // features per head
constexpr int A1S = 200;   // LDS stride (bf16) for x buffer   (192+8; 400B, 16B-aligned rows)
constexpr int A2S = 392;   // LDS stride (bf16) for hcat buffer (384+8; 784B, 16B-aligned rows)
constexpr int WHS = 196;   // LDS stride (fp32) for Wh buffer

__device__ __forceinline__ short f2bf(float f) {
  union { float f; unsigned u; } v; v.f = f;
  unsigned r = v.u + 0x7FFFu + ((v.u >> 16) & 1u);  // RNE
  return (short)(r >> 16);
}

// ---- prep: swizzle W1,W2,Wo (fp32 row-major [K][192]) -> bf16 B-frag-major ----
// Fragment layout (mfma_f32_16x16x32_bf16 B operand): lane l holds B[k][n] with
// n = nt*16 + (l&15), k = ks*32 + (l>>4)*8 + j, j=0..7. Dest elem index:
// ((nt*ksteps + ks)*64 + l)*8 + j. W1f @0, W2f @36864, Wof @73728 (shorts).
__global__ void prep_kernel(const float* __restrict__ W1, const float* __restrict__ W2,
                            const float* __restrict__ Wo, short* __restrict__ dstws) {
  int idx = blockIdx.x * 256 + threadIdx.x;   // grid = 576*256 = 147456 exact
  const float* src; short* dst; int ksteps;
  if (idx < 36864)      { src = W1; dst = dstws;          ksteps = 6;  }
  else if (idx < 73728) { src = W2; dst = dstws + 36864; idx -= 36864; ksteps = 6;  }
  else                  { src = Wo; dst = dstws + 73728; idx -= 73728; ksteps = 12; }
  int j = idx & 7, l = (idx >> 3) & 63, fi = idx >> 9;
  int nt = fi / ksteps, ks = fi - nt * ksteps;
  int k = ks * 32 + ((l >> 4) << 3) + j;
  int n = (nt << 4) + (l & 15);
  dst[idx] = f2bf(src[k * 192 + n]);
}

// ---- MFMA GEMM: [22(x32 pad)][K]bf16 (LDS) @ [K][192]bf16 (global frags) -> wh fp32 LDS ----
__device__ __attribute__((always_inline)) inline void mfma_gemm(
    const short* Alds, int astride, const s16x8* Bf, int ksteps,
    float* whp, int lane, int wave)
{
  f32x4 acc[2][3] = {};
  const int m0 = lane & 15, kg = (lane >> 4) & 3;
  for (int ks = 0; ks < ksteps; ++ks) {
    const short* ap = Alds + ks * 32 + kg * 8;
    s16x8 av0 = *(const s16x8*)(ap + m0 * astride);         // ds_read_b128
    s16x8 av1 = *(const s16x8*)(ap + (m0 + 16) * astride);  // pad rows -> discarded D rows
    const s16x8* bp = Bf + ks * 64 + lane;
    #pragma unroll
    for (int t = 0; t < 3; ++t) {
      s16x8 bv = bp[(wave * 3 + t) * ksteps * 64];          // global_load_dwordx4, L2-hot
      acc[0][t] = __builtin_amdgcn_mfma_f32_16x16x32_bf16(av0, bv, acc[0][t], 0, 0, 0);
      acc[1][t] = __builtin_amdgcn_mfma_f32_16x16x32_bf16(av1, bv, acc[1][t], 0, 0, 0);
    }
  }
  // D layout: col = lane&15 (+16*nt), row = (lane>>4)*4 + r (+16*mtile)
  #pragma unroll
  for (int m = 0; m < 2; ++m) {
    #pragma unroll
    for (int t = 0; t < 3; ++t) {
      int col = (wave * 3 + t) * 16 + m0;
      int rb  = m * 16 + kg * 4;
      #pragma unroll
      for (int r = 0; r < 4; ++r)
        if (rb + r < NN) whp[(rb + r) * WHS + col] = acc[m][t][r];
    }
  }
}

// ---- e_src/e_dst dots: threads 0..43 (n = tid/2, which = tid&1) ----
__device__ __attribute__((always_inline)) inline void attn_rows(
    const float* whp, const float* __restrict__ av, float* es, float* ed, int tid)
{
  if (tid < 2 * NN) {
    const int n = tid >> 1, w = tid & 1;
    const float* a = av + w * FF;
    float s = 0.f;
    #pragma unroll 4
    for (int o = 0; o < FF; ++o) s += whp[n * WHS + o] * a[o];
    if (w) ed[n] = s; else es[n] = s;
  }
}

// ---- masked-softmax rows: threads 0..21 ----
__device__ __attribute__((always_inline)) inline void softmax22(
    const float* __restrict__ adj, const float* es, const float* ed, float* att, int tid)
{
  if (tid < NN) {
    const int i = tid;
    float ei[NN];
    float esi = es[i];
    float mx = -1e30f;
    #pragma unroll
    for (int j = 0; j < NN; ++j) {
      float e = esi + ed[j];
      e = e > 0.f ? e : 0.2f * e;                 // LeakyReLU(0.2) then mask (per ref)
      e = (adj[i * NN + j] > 0.f) ? e : -9e15f;   // NEG_INF
      ei[j] = e; mx = fmaxf(mx, e);
    }
    float sum = 0.f;
    #pragma unroll
    for (int j = 0; j < NN; ++j) { float p = expf(ei[j] - mx); ei[j] = p; sum += p; }
    float inv = 1.f / sum;
    #pragma unroll
    for (int j = 0; j < NN; ++j) att[i * 24 + j] = ei[j] * inv;
    att[i * 24 + 22] = 0.f; att[i * 24 + 23] = 0.f;  // zero pad for float4 consumer
  }
}

__global__ __launch_bounds__(256) void gat_main(
    const float* __restrict__ x, const float* __restrict__ adj,
    const float* __restrict__ a1, const float* __restrict__ a2,
    const float* __restrict__ ao, const short* __restrict__ wsb,
    float* __restrict__ out)
{
  __shared__ __align__(16) short As1[32 * A1S];   // x bf16, rows 22..31 = don't-care pad
  __shared__ __align__(16) short As2[32 * A2S];   // hcat bf16
  __shared__ __align__(16) float wh [NN * WHS];   // current head's Wh (fp32)
  __shared__ __align__(16) float att[NN * 24];
  __shared__ float es[NN], ed[NN];

  const int tid  = threadIdx.x;
  const int lane = tid & 63, wave = tid >> 6;
  const size_t b = blockIdx.x;
  const float* xb = x + b * (size_t)(NN * FF);

  // stage x -> bf16 LDS
  for (int idx = tid; idx < NN * FF; idx += 256) {
    int n = idx / FF, f = idx - n * FF;
    As1[n * A1S + f] = f2bf(xb[idx]);
  }
  __syncthreads();

  // ---- heads 1,2 ----
  for (int h = 0; h < 2; ++h) {
    mfma_gemm(As1, A1S, (const s16x8*)wsb + h * 4608, 6, wh, lane, wave);
    __syncthreads();
    attn_rows(wh, h ? a2 : a1, es, ed, tid);
    __syncthreads();
    softmax22(adj, es, ed, att, tid);
    __syncthreads();
    if (tid < FF) {                      // out_h = elu(att @ Wh) -> As2 bf16
      const int o = tid;
      float wc[24];
      #pragma unroll
      for (int j2 = 0; j2 < NN; ++j2) wc[j2] = wh[j2 * WHS + o];
      wc[22] = 0.f; wc[23] = 0.f;
      for (int n = 0; n < NN; ++n) {
        const float4* ar = (const float4*)(att + n * 24);   // ds_read_b128 broadcast
        float s = 0.f;
        #pragma unroll
        for (int q = 0; q < 6; ++q) {
          float4 a4 = ar[q];
          s += a4.x * wc[4*q] + a4.y * wc[4*q+1] + a4.z * wc[4*q+2] + a4.w * wc[4*q+3];
        }
        float v = s > 0.f ? s : expm1f(s);                  // elu (concat head)
        As2[n * A2S + h * FF + o] = f2bf(v);
      }
    }
    __syncthreads();
  }

  // ---- output head: Wh_o = hcat @ Wo (K=384) ----
  mfma_gemm(As2, A2S, (const s16x8*)wsb + 9216, 12, wh, lane, wave);
  __syncthreads();
  attn_rows(wh, ao, es, ed, tid);
  __syncthreads();
  softmax22(adj, es, ed, att, tid);
  __syncthreads();
  if (tid < FF) {                        // y = elu(att_o @ Wh_o) + x
    const int o = tid;
    float wc[24];
    #pragma unroll
    for (int j2 = 0; j2 < NN; ++j2) wc[j2] = wh[j2 * WHS + o];
    wc[22] = 0.f; wc[23] = 0.f;
    float* ob = out + b * (size_t)(NN * FF);
    for (int n = 0; n < NN; ++n) {
      const float4* ar = (const float4*)(att + n * 24);
      float s = 0.f;
      #pragma unroll
      for (int q = 0; q < 6; ++q) {
        float4 a4 = ar[q];
        s += a4.x * wc[4*q] + a4.y * wc[4*q+1] + a4.z * wc[4*q+2] + a4.w * wc[4*q+3];
      }
      float v = s > 0.f ? s : expm1f(s);
      ob[n * FF + o] = v + xb[n * FF + o];
    }
  }
}

extern "C" void kernel_launch(void* const* d_in, const int* in_sizes, int n_in,
                              void* d_out, int out_size, void* d_ws, size_t ws_size,
                              hipStream_t stream) {
  const float* x   = (const float*)d_in[0];
  const float* adj = (const float*)d_in[1];
  const float* W1  = (const float*)d_in[2];
  const float* a1  = (const float*)d_in[3];
  const float* W2  = (const float*)d_in[4];
  const float* a2  = (const float*)d_in[5];
  const float* Wo  = (const float*)d_in[6];
  const float* ao  = (const float*)d_in[7];
  float* out = (float*)d_out;
  short* wsb = (short*)d_ws;   // 294912 bytes used: W1f | W2f | Wof (bf16 frag-major)

  const int batch = in_sizes[0] / (NN * FF);   // 16384
  prep_kernel<<<576, 256, 0, stream>>>(W1, W2, Wo, wsb);
  gat_main<<<batch, 256, 0, stream>>>(x, adj, a1, a2, ao, wsb, out);
}

// Round 2
// 1120.821 us; speedup vs baseline: 1.4796x; 1.4796x over previous
//
#include <hip/hip_runtime.h>

// ST_GCNA: 3-head GAT, b=16384, N=22, F=H=192.
// R2: all-MFMA design. e_src/e_dst folded into GEMM as extra B-tile (cols =
// W@a_src, W@a_dst). att@Wh done with MFMA (Wh stored transposed bf16 in LDS).
// Output-head GEMM accumulated in registers across heads (no hcat buffer).

typedef __attribute__((ext_vector_type(8))) short s16x8;
typedef __attribute__((ext_vector_type(4))) short s16x4;
typedef __attribute__((ext_vector_type(4))) float f32x4;

constexpr int NN = 22;
constexpr int FF = 192;
constexpr int AS = 200;   // stride (shorts) for As1/Ah row-major A buffers
constexpr int TS = 40;    // stride (shorts) for attA rows / WhT cols

__device__ __forceinline__ short f2bf(float f) {
  union { float f; unsigned u; } v; v.f = f;
  unsigned r = v.u + 0x7FFFu + ((v.u >> 16) & 1u);  // RNE
  return (short)(r >> 16);
}

// ---- prep 1: w-vectors  w_src = W @ a[:192], w_dst = W @ a[192:384] ----
// vecs layout (floats): [0:192) w1s [192:384) w1d [384:576) w2s [576:768) w2d
//                       [768:1152) wos [1152:1536) wod
__global__ void prep_vec(const float* __restrict__ W1, const float* __restrict__ a1,
                         const float* __restrict__ W2, const float* __restrict__ a2,
                         const float* __restrict__ Wo, const float* __restrict__ ao,
                         float* __restrict__ vecs) {
  int t = blockIdx.x * 256 + threadIdx.x;
  if (t >= 1536) return;
  const float* W; const float* a; int k;
  if (t < 384)      { W = W1; k = t % 192;            a = a1 + (t / 192) * 192; }
  else if (t < 768) { int u = t - 384; W = W2; k = u % 192; a = a2 + (u / 192) * 192; }
  else              { int u = t - 768; W = Wo; k = u % 384; a = ao + (u / 384) * 192; }
  float s = 0.f;
  for (int o = 0; o < 192; ++o) s += W[k * 192 + o] * a[o];
  vecs[t] = s;
}

// ---- prep 2: pack W1,W2,Wo into bf16 B-fragment-major + extra e-tile ----
// frag elem idx = ((nt*ksteps + ks)*64 + lane)*8 + j ; lane holds B[k][n],
// n = nt*16 + (lane&15), k = ks*32 + (lane>>4)*8 + j. Tile 12: col0=w_src,
// col1=w_dst, rest 0. W1f @0 (39936 sh), W2f @39936, Wof @79872 (79872 sh).
__global__ void prep_pack(const float* __restrict__ W1, const float* __restrict__ W2,
                          const float* __restrict__ Wo, const float* __restrict__ vecs,
                          short* __restrict__ dst) {
  int idx = blockIdx.x * 256 + threadIdx.x;   // grid 624*256 = 159744 exact
  const float* W; int off, ksteps, v0, v1;
  if (idx < 39936)      { W = W1; off = 0;     ksteps = 6;  v0 = 0;   v1 = 192;  }
  else if (idx < 79872) { W = W2; off = 39936; ksteps = 6;  v0 = 384; v1 = 576;  }
  else                  { W = Wo; off = 79872; ksteps = 12; v0 = 768; v1 = 1152; }
  int local = idx - off;
  int j = local & 7, l = (local >> 3) & 63, fi = local >> 9;
  int nt = fi / ksteps, ks = fi - nt * ksteps;
  int k = ks * 32 + ((l >> 4) << 3) + j;
  int nl = l & 15;
  float v;
  if (nt < 12) v = W[k * 192 + nt * 16 + nl];
  else         v = (nl == 0) ? vecs[v0 + k] : (nl == 1) ? vecs[v1 + k] : 0.f;
  dst[idx] = f2bf(v);
}

struct Accs { f32x4 a[2][3]; f32x4 e[2]; };

__device__ __forceinline__ void zacc(Accs& a) {
  #pragma unroll
  for (int m = 0; m < 2; ++m) {
    #pragma unroll
    for (int t = 0; t < 3; ++t) a.a[m][t] = (f32x4){0.f, 0.f, 0.f, 0.f};
    a.e[m] = (f32x4){0.f, 0.f, 0.f, 0.f};
  }
}

// GEMM over 6 ksteps (K=192 slice): A [32][K] bf16 LDS, B frag-major global.
// Waves own n-tiles {3w..3w+2}; wave 3 also the e-tile (tile 12).
__device__ __attribute__((always_inline)) inline void gemm6(
    const short* A, const s16x8* __restrict__ B, int ksTot, int ksOff,
    Accs& ac, int m0, int kg, int wave, int lane) {
  for (int ks = 0; ks < 6; ++ks) {
    const short* ap = A + ks * 32 + kg * 8;
    s16x8 av0 = *(const s16x8*)(ap + m0 * AS);
    s16x8 av1 = *(const s16x8*)(ap + (m0 + 16) * AS);
    #pragma unroll
    for (int t = 0; t < 3; ++t) {
      s16x8 bv = B[((wave * 3 + t) * ksTot + ksOff + ks) * 64 + lane];
      ac.a[0][t] = __builtin_amdgcn_mfma_f32_16x16x32_bf16(av0, bv, ac.a[0][t], 0, 0, 0);
      ac.a[1][t] = __builtin_amdgcn_mfma_f32_16x16x32_bf16(av1, bv, ac.a[1][t], 0, 0, 0);
    }
    if (wave == 3) {
      s16x8 bv = B[(12 * ksTot + ksOff + ks) * 64 + lane];
      ac.e[0] = __builtin_amdgcn_mfma_f32_16x16x32_bf16(av0, bv, ac.e[0], 0, 0, 0);
      ac.e[1] = __builtin_amdgcn_mfma_f32_16x16x32_bf16(av1, bv, ac.e[1], 0, 0, 0);
    }
  }
}

// D -> WhT (bf16, transposed: WhT[col*TS + row]) + es/ed from e-tile.
// Pad D rows 22..31 are exact zeros (A pad rows zeroed) so unconditional
// writes keep WhT pad rows zero -> no 0*garbage NaNs in the PV MFMA.
__device__ __attribute__((always_inline)) inline void storeD(
    const Accs& ac, short* WhTp, float* esp, float* edp, int m0, int kg, int wave) {
  #pragma unroll
  for (int m = 0; m < 2; ++m)
    #pragma unroll
    for (int t = 0; t < 3; ++t) {
      int col = (wave * 3 + t) * 16 + m0;
      int row0 = m * 16 + kg * 4;
      s16x4 p = { f2bf(ac.a[m][t][0]), f2bf(ac.a[m][t][1]),
                  f2bf(ac.a[m][t][2]), f2bf(ac.a[m][t][3]) };
      *(s16x4*)&WhTp[col * TS + row0] = p;   // ds_write_b64
    }
  if (wave == 3 && m0 < 2) {
    float* dst = m0 ? edp : esp;
    #pragma unroll
    for (int m = 0; m < 2; ++m) {
      int row0 = m * 16 + kg * 4;
      #pragma unroll
      for (int r = 0; r < 4; ++r)
        if (row0 + r < NN) dst[row0 + r] = ac.e[m][r];
    }
  }
}

// P @ Wh via MFMA: A = attA (bf16 row-major [32][32], zero pad cols),
// B = WhT (bf16 col-major). K=32 single step, 3 n-tiles per wave.
__device__ __attribute__((always_inline)) inline void pv22(
    const short* attAp, const short* WhTp, f32x4 pa[2][3], int m0, int kg, int wave) {
  s16x8 av0 = *(const s16x8*)(attAp + m0 * TS + kg * 8);
  s16x8 av1 = *(const s16x8*)(attAp + (m0 + 16) * TS + kg * 8);
  #pragma unroll
  for (int t = 0; t < 3; ++t) {
    int col = (wave * 3 + t) * 16 + m0;
    s16x8 bv = *(const s16x8*)(WhTp + col * TS + kg * 8);
    pa[0][t] = __builtin_amdgcn_mfma_f32_16x16x32_bf16(av0, bv, pa[0][t], 0, 0, 0);
    pa[1][t] = __builtin_amdgcn_mfma_f32_16x16x32_bf16(av1, bv, pa[1][t], 0, 0, 0);
  }
}

__global__ __launch_bounds__(256, 3) void gat_main(
    const float* __restrict__ x, const float* __restrict__ adj,
    const short* __restrict__ wsb, float* __restrict__ out) {
  __shared__ __align__(16) short As1[32 * AS];   // x bf16, rows 22..31 zeroed
  __shared__ __align__(16) short Ah [32 * AS];   // per-head output bf16, pad zeroed
  __shared__ __align__(16) short attA[32 * TS];  // att bf16 A-layout
  __shared__ __align__(16) short WhT[FF * TS];   // Wh^T bf16 (B-operand layout)
  __shared__ float es[NN], ed[NN];
  __shared__ unsigned adjm[NN];

  const int tid = threadIdx.x, lane = tid & 63, wave = tid >> 6;
  const int m0 = lane & 15, kg = (lane >> 4) & 3;
  const size_t b = blockIdx.x;
  const float* xb = x + b * (size_t)(NN * FF);

  // stage x -> bf16 LDS (float4 loads, b64 LDS writes)
  for (int i4 = tid; i4 < 1056; i4 += 256) {
    int row = i4 / 48, c = (i4 - row * 48) * 4;
    float4 v = ((const float4*)xb)[i4];
    s16x4 p = { f2bf(v.x), f2bf(v.y), f2bf(v.z), f2bf(v.w) };
    *(s16x4*)&As1[row * AS + c] = p;
  }
  { // zero pad rows 22..31 of As1 and Ah (keeps all D pad rows finite zero)
    int* z1 = (int*)(As1 + NN * AS);
    int* z2 = (int*)(Ah + NN * AS);
    for (int i = tid; i < 1000; i += 256) { z1[i] = 0; z2[i] = 0; }
  }
  if (tid < NN) {  // adjacency bitmask
    unsigned m = 0;
    for (int j = 0; j < NN; ++j) m |= (adj[tid * NN + j] > 0.f ? 1u : 0u) << j;
    adjm[tid] = m;
  }
  __syncthreads();

  const s16x8* BW  = (const s16x8*)wsb;          // W1f frags
  const s16x8* BWo = (const s16x8*)wsb + 9984;   // Wof frags

  Accs aco; zacc(aco);                            // persistent Wh_o accumulator

  for (int h = 0; h < 2; ++h) {
    // GEMM: Wh = x @ W_h (+ e-tile) -> WhT bf16, es/ed fp32
    Accs ach; zacc(ach);
    gemm6(As1, BW + h * 4992, 6, 0, ach, m0, kg, wave, lane);
    storeD(ach, WhT, es, ed, m0, kg, wave);
    __syncthreads();

    // masked softmax rows (wave 0) -> attA bf16 (cols 22..31 zeroed)
    if (tid < NN) {
      unsigned msk = adjm[tid];
      float esi = es[tid];
      float p[NN]; float mx = -3e38f;
      #pragma unroll
      for (int j = 0; j < NN; ++j) {
        float e = esi + ed[j];
        e = e > 0.f ? e : 0.2f * e;
        e = ((msk >> j) & 1) ? e : -9e15f;
        p[j] = e; mx = fmaxf(mx, e);
      }
      float sum = 0.f;
      #pragma unroll
      for (int j = 0; j < NN; ++j) { float q = __expf(p[j] - mx); p[j] = q; sum += q; }
      float inv = 1.f / sum;
      int* row = (int*)(attA + tid * TS);
      #pragma unroll
      for (int j2 = 0; j2 < 11; ++j2) {
        unsigned lo = (unsigned short)f2bf(p[2 * j2] * inv);
        unsigned hi = (unsigned short)f2bf(p[2 * j2 + 1] * inv);
        row[j2] = (int)(lo | (hi << 16));
      }
      #pragma unroll
      for (int j2 = 11; j2 < 16; ++j2) row[j2] = 0;
    }
    __syncthreads();

    // out_h = elu(att @ Wh) -> Ah bf16
    f32x4 pa[2][3];
    #pragma unroll
    for (int m = 0; m < 2; ++m)
      #pragma unroll
      for (int t = 0; t < 3; ++t) pa[m][t] = (f32x4){0.f, 0.f, 0.f, 0.f};
    pv22(attA, WhT, pa, m0, kg, wave);
    #pragma unroll
    for (int m = 0; m < 2; ++m)
      #pragma unroll
      for (int t = 0; t < 3; ++t) {
        int col = (wave * 3 + t) * 16 + m0;
        int row0 = m * 16 + kg * 4;
        #pragma unroll
        for (int r = 0; r < 4; ++r) {
          int row = row0 + r;
          if (row < NN) {
            float v = pa[m][t][r];
            v = v > 0.f ? v : expm1f(v);
            Ah[row * AS + col] = f2bf(v);
          }
        }
      }
    __syncthreads();

    // accumulate Wh_o += h_h @ Wo[h*192:(h+1)*192, :] (+ e-tile) in registers
    gemm6(Ah, BWo, 12, 6 * h, aco, m0, kg, wave, lane);
  }

  // output head
  storeD(aco, WhT, es, ed, m0, kg, wave);
  __syncthreads();
  if (tid < NN) {
    unsigned msk = adjm[tid];
    float esi = es[tid];
    float p[NN]; float mx = -3e38f;
    #pragma unroll
    for (int j = 0; j < NN; ++j) {
      float e = esi + ed[j];
      e = e > 0.f ? e : 0.2f * e;
      e = ((msk >> j) & 1) ? e : -9e15f;
      p[j] = e; mx = fmaxf(mx, e);
    }
    float sum = 0.f;
    #pragma unroll
    for (int j = 0; j < NN; ++j) { float q = __expf(p[j] - mx); p[j] = q; sum += q; }
    float inv = 1.f / sum;
    int* row = (int*)(attA + tid * TS);
    #pragma unroll
    for (int j2 = 0; j2 < 11; ++j2) {
      unsigned lo = (unsigned short)f2bf(p[2 * j2] * inv);
      unsigned hi = (unsigned short)f2bf(p[2 * j2 + 1] * inv);
      row[j2] = (int)(lo | (hi << 16));
    }
    #pragma unroll
    for (int j2 = 11; j2 < 16; ++j2) row[j2] = 0;
  }
  __syncthreads();

  f32x4 pa[2][3];
  #pragma unroll
  for (int m = 0; m < 2; ++m)
    #pragma unroll
    for (int t = 0; t < 3; ++t) pa[m][t] = (f32x4){0.f, 0.f, 0.f, 0.f};
  pv22(attA, WhT, pa, m0, kg, wave);
  float* ob = out + b * (size_t)(NN * FF);
  #pragma unroll
  for (int m = 0; m < 2; ++m)
    #pragma unroll
    for (int t = 0; t < 3; ++t) {
      int col = (wave * 3 + t) * 16 + m0;
      int row0 = m * 16 + kg * 4;
      #pragma unroll
      for (int r = 0; r < 4; ++r) {
        int row = row0 + r;
        if (row < NN) {
          float v = pa[m][t][r];
          v = v > 0.f ? v : expm1f(v);
          ob[row * FF + col] = v + xb[row * FF + col];
        }
      }
    }
}

extern "C" void kernel_launch(void* const* d_in, const int* in_sizes, int n_in,
                              void* d_out, int out_size, void* d_ws, size_t ws_size,
                              hipStream_t stream) {
  const float* x   = (const float*)d_in[0];
  const float* adj = (const float*)d_in[1];
  const float* W1  = (const float*)d_in[2];
  const float* a1  = (const float*)d_in[3];
  const float* W2  = (const float*)d_in[4];
  const float* a2  = (const float*)d_in[5];
  const float* Wo  = (const float*)d_in[6];
  const float* ao  = (const float*)d_in[7];
  float* out = (float*)d_out;
  short* wsb  = (short*)d_ws;                        // 319488 B frags
  float* vecs = (float*)((char*)d_ws + 319488);      // + 6144 B w-vectors

  const int batch = in_sizes[0] / (NN * FF);         // 16384
  prep_vec <<<6,   256, 0, stream>>>(W1, a1, W2, a2, Wo, ao, vecs);
  prep_pack<<<624, 256, 0, stream>>>(W1, W2, Wo, vecs, wsb);
  gat_main <<<batch, 256, 0, stream>>>(x, adj, wsb, out);
}